// Round 1
// baseline (1464.787 us; speedup 1.0000x reference)
//
#include <hip/hip_runtime.h>

// SNN: T=200 steps, B=256, IN=784, N=1024, OUT=10
// Key algebra: W_rec = -0.5*(ones - I)  =>  prev@W_rec = -0.5*(S_b - prev[b,j])
//   (exact in fp32: all partial sums are multiples of 0.5, |.| <= 512)
// net_in[t] = x_t @ W_in is time-independent => one big GEMM up front,
// written into d_out's hidden_spikes region (same size), then overwritten
// in-place by the spike scan.

#define TT 200
#define BB 256
#define KK 784
#define NN 1024
#define OO 10

__device__ __forceinline__ float shfl_down64(float v, int d) {
  return __shfl_down(v, d, 64);
}

// ---------------- Phase 1: net = X(51200x784) @ W(784x1024), fp32 ----------
// BM=BN=64, BK=16, 256 threads, 4x4 micro-tile per thread.
__global__ __launch_bounds__(256)
void gemm_net(const float* __restrict__ X, const float* __restrict__ W,
              float* __restrict__ C) {
  __shared__ float As[16][64];   // [k][m] (A staged transposed)
  __shared__ float Bs[16][64];   // [k][n]
  const int tid = threadIdx.x;
  const int m0 = blockIdx.x * 64;
  const int n0 = blockIdx.y * 64;
  const int tr = (tid >> 4) * 4;       // tile-row base 0..60
  const int tc = (tid & 15) * 4;       // tile-col base 0..60
  const int arow = tid >> 2;           // 0..63
  const int ak   = (tid & 3) * 4;      // 0,4,8,12
  const int brow = tid >> 4;           // 0..15
  const int bc   = (tid & 15) * 4;     // 0..60

  float acc[4][4] = {};

  for (int k0 = 0; k0 < KK; k0 += 16) {
    float4 av = *(const float4*)(X + (m0 + arow) * KK + k0 + ak);
    float4 bv = *(const float4*)(W + (k0 + brow) * NN + n0 + bc);
    __syncthreads();
    As[ak + 0][arow] = av.x;
    As[ak + 1][arow] = av.y;
    As[ak + 2][arow] = av.z;
    As[ak + 3][arow] = av.w;
    *(float4*)&Bs[brow][bc] = bv;
    __syncthreads();
#pragma unroll
    for (int k = 0; k < 16; ++k) {
      float4 a = *(const float4*)&As[k][tr];
      float4 b = *(const float4*)&Bs[k][tc];
      float aa[4] = {a.x, a.y, a.z, a.w};
      float bb[4] = {b.x, b.y, b.z, b.w};
#pragma unroll
      for (int i = 0; i < 4; ++i)
#pragma unroll
        for (int j = 0; j < 4; ++j)
          acc[i][j] = fmaf(aa[i], bb[j], acc[i][j]);
    }
  }
#pragma unroll
  for (int i = 0; i < 4; ++i) {
    float4 v = {acc[i][0], acc[i][1], acc[i][2], acc[i][3]};
    *(float4*)(C + (m0 + tr + i) * NN + n0 + tc) = v;
  }
}

// ---------------- Phase 2: sequential scan, one block per batch row --------
// hid holds net on entry (from phase 1); overwritten in place with spikes.
__global__ __launch_bounds__(256)
void snn_scan(float* __restrict__ hid, const float* __restrict__ Wout,
              float* __restrict__ logits) {
  constexpr float V_REST = -65.0f, THRESH0 = -50.0f, TAU_M = 20.0f,
                  TAU_TH = 100.0f, BETA = 5.0f, DT = 1.0f;
  const int b = blockIdx.x;
  const int tid = threadIdx.x;
  __shared__ float s_part[4];
  __shared__ float s_log[4][OO];

  float mp[4], th[4], prev[4], cnt[4], net[4];
#pragma unroll
  for (int k = 0; k < 4; ++k) {
    mp[k] = V_REST; th[k] = THRESH0; prev[k] = 0.0f; cnt[k] = 0.0f;
  }
  float S = 0.0f;                       // total spikes in this row, prev step
  const int base = b * NN + tid;        // j = tid + 256*k

  // prefetch net[t=0]
#pragma unroll
  for (int k = 0; k < 4; ++k) net[k] = hid[base + k * 256];

  for (int t = 0; t < TT; ++t) {
    float local = 0.0f;
    float sp[4];
#pragma unroll
    for (int k = 0; k < 4; ++k) {
      // exact recurrent term: prev@W_rec = -0.5*(S - prev)
      float rec = -0.5f * (S - prev[k]);
      float nv  = net[k] + rec;                       // matches np add order
      float m   = mp[k] + (V_REST - mp[k]) / TAU_M;   // true division
      m = m + nv * DT;
      float s = (m >= th[k]) ? 1.0f : 0.0f;
      th[k] = (th[k] + BETA * s) - ((th[k] - THRESH0) / TAU_TH) * DT;
      mp[k] = (s > 0.0f) ? V_REST : m;
      cnt[k] += s;
      prev[k] = s;
      sp[k] = s;
      local += s;
    }
    const int off = t * (BB * NN) + base;
#pragma unroll
    for (int k = 0; k < 4; ++k) hid[off + k * 256] = sp[k];

    // prefetch next step's net (independent of this step's results)
    if (t + 1 < TT) {
      const int noff = (t + 1) * (BB * NN) + base;
#pragma unroll
      for (int k = 0; k < 4; ++k) net[k] = hid[noff + k * 256];
    }

    // block-reduce spike count -> S for next step (integer-valued: exact)
#pragma unroll
    for (int d = 32; d > 0; d >>= 1) local += shfl_down64(local, d);
    __syncthreads();                    // protect s_part reads of prev iter
    if ((tid & 63) == 0) s_part[tid >> 6] = local;
    __syncthreads();
    S = s_part[0] + s_part[1] + s_part[2] + s_part[3];
  }

  // logits[b,o] = sum_j cnt[b,j] * Wout[j,o]
  float lg[OO];
#pragma unroll
  for (int o = 0; o < OO; ++o) lg[o] = 0.0f;
#pragma unroll
  for (int k = 0; k < 4; ++k) {
    const int j = tid + k * 256;
#pragma unroll
    for (int o = 0; o < OO; ++o) lg[o] = fmaf(cnt[k], Wout[j * OO + o], lg[o]);
  }
#pragma unroll
  for (int o = 0; o < OO; ++o) {
    float v = lg[o];
#pragma unroll
    for (int d = 32; d > 0; d >>= 1) v += shfl_down64(v, d);
    if ((tid & 63) == 0) s_log[tid >> 6][o] = v;
  }
  __syncthreads();
  if (tid < OO)
    logits[b * OO + tid] =
        s_log[0][tid] + s_log[1][tid] + s_log[2][tid] + s_log[3][tid];
}

extern "C" void kernel_launch(void* const* d_in, const int* in_sizes, int n_in,
                              void* d_out, int out_size, void* d_ws,
                              size_t ws_size, hipStream_t stream) {
  const float* X    = (const float*)d_in[0];  // input_spikes [200][256][784]
  const float* Win  = (const float*)d_in[1];  // [784][1024]
  // d_in[2] = W_rec — unused (exact closed form)
  const float* Wout = (const float*)d_in[3];  // [1024][10]

  float* logits = (float*)d_out;              // [256][10]
  float* hid    = (float*)d_out + BB * OO;    // [200][256][1024]

  dim3 g1(TT * BB / 64, NN / 64);             // 800 x 16 blocks
  gemm_net<<<g1, 256, 0, stream>>>(X, Win, hid);
  snn_scan<<<BB, 256, 0, stream>>>(hid, Wout, logits);
}

// Round 2
// 1244.464 us; speedup vs baseline: 1.1770x; 1.1770x over previous
//
#include <hip/hip_runtime.h>

// SNN: T=200, B=256, IN=784, N=1024, OUT=10
// W_rec = -0.5*(ones - I) => prev@W_rec = -0.5*(S_b - prev[b,j])  (exact in
// fp32: all partial sums are multiples of 0.5 with |.| <= 512, so numpy's
// BLAS order and ours agree bit-for-bit).
// net_in[t] = x_t @ W_in is time-independent => one big fp32 GEMM up front
// into d_out's hidden_spikes region, then an in-place spike scan.
//
// NUMERICS CONTRACT: the dynamics are knife-edge (absmax 512 of 611 comes
// from a single marginal spike-step flip vs BLAS summation order). The GEMM
// must keep a single ascending-k fmaf chain per output element — bit-identical
// to the round-1 passing kernel. No MFMA/bf16, no split-K, no reassociation.

#define TT 200
#define BB 256
#define KK 784
#define NN 1024
#define OO 10

// ---------------- Phase 1: net = X(51200x784) @ W(784x1024), fp32 ----------
// 128x128 tile, BK=16, 256 threads, 8x8 micro-tile (as 2x2 quadrants of 4x4).
__global__ __launch_bounds__(256)
void gemm_net(const float* __restrict__ X, const float* __restrict__ W,
              float* __restrict__ C) {
  __shared__ float As[16][128];   // [k][m] (A staged transposed)
  __shared__ float Bs[16][128];   // [k][n]
  float4 (*As4)[32] = (float4(*)[32])As;
  float4 (*Bs4)[32] = (float4(*)[32])Bs;

  const int tid = threadIdx.x;
  const int n0 = blockIdx.x * 128;
  const int m0 = blockIdx.y * 128;
  const int tx = tid & 15;             // 0..15 -> cols tx*4, 64+tx*4
  const int ty = tid >> 4;             // 0..15 -> rows ty*4, 64+ty*4
  const int arow = tid >> 1;           // 0..127
  const int ak   = (tid & 1) * 8;      // 0 or 8
  const int brow = tid >> 5;           // 0..7 (and +8)
  const int bc   = (tid & 31) * 4;     // 0..124

  float acc[2][2][4][4] = {};

  for (int k0 = 0; k0 < KK; k0 += 16) {
    // global loads (before barrier: overlap with previous tile's compute)
    const float* ap = X + (size_t)(m0 + arow) * KK + k0 + ak;
    float4 a0 = *(const float4*)(ap);
    float4 a1 = *(const float4*)(ap + 4);
    float4 b0 = *(const float4*)(W + (size_t)(k0 + brow) * NN + n0 + bc);
    float4 b1 = *(const float4*)(W + (size_t)(k0 + brow + 8) * NN + n0 + bc);
    __syncthreads();
    // As transpose-write: bank = arow%32, 2 lanes/bank (2-way = free)
    As[ak + 0][arow] = a0.x;
    As[ak + 1][arow] = a0.y;
    As[ak + 2][arow] = a0.z;
    As[ak + 3][arow] = a0.w;
    As[ak + 4][arow] = a1.x;
    As[ak + 5][arow] = a1.y;
    As[ak + 6][arow] = a1.z;
    As[ak + 7][arow] = a1.w;
    // Bs writes: lane-consecutive float4 -> conflict-free
    *(float4*)&Bs[brow][bc] = b0;
    *(float4*)&Bs[brow + 8][bc] = b1;
    __syncthreads();
#pragma unroll
    for (int k = 0; k < 16; ++k) {
      float4 A0 = As4[k][ty];        // broadcast (free)
      float4 A1 = As4[k][16 + ty];
      float4 B0 = Bs4[k][tx];        // 2-way (free)
      float4 B1 = Bs4[k][16 + tx];
      float a[2][4] = {{A0.x, A0.y, A0.z, A0.w}, {A1.x, A1.y, A1.z, A1.w}};
      float b[2][4] = {{B0.x, B0.y, B0.z, B0.w}, {B1.x, B1.y, B1.z, B1.w}};
#pragma unroll
      for (int qi = 0; qi < 2; ++qi)
#pragma unroll
        for (int qj = 0; qj < 2; ++qj)
#pragma unroll
          for (int i = 0; i < 4; ++i)
#pragma unroll
            for (int j = 0; j < 4; ++j)
              acc[qi][qj][i][j] = fmaf(a[qi][i], b[qj][j], acc[qi][qj][i][j]);
    }
  }
#pragma unroll
  for (int qi = 0; qi < 2; ++qi)
#pragma unroll
    for (int i = 0; i < 4; ++i) {
      const int r = m0 + qi * 64 + ty * 4 + i;
#pragma unroll
      for (int qj = 0; qj < 2; ++qj) {
        float4 v = {acc[qi][qj][i][0], acc[qi][qj][i][1],
                    acc[qi][qj][i][2], acc[qi][qj][i][3]};
        *(float4*)(C + (size_t)r * NN + n0 + qj * 64 + tx * 4) = v;
      }
    }
}

// ---------------- Phase 2: sequential scan, one block per batch row --------
// 1024 threads (1 neuron each, 16 waves). hid holds net on entry; overwritten
// in place with spikes. One barrier per step (parity-buffered partials).
__global__ __launch_bounds__(1024)
void snn_scan(float* __restrict__ hid, const float* __restrict__ Wout,
              float* __restrict__ logits) {
  constexpr float V_REST = -65.0f, THRESH0 = -50.0f, TAU_M = 20.0f,
                  TAU_TH = 100.0f, BETA = 5.0f, DT = 1.0f;
  const int b = blockIdx.x;
  const int tid = threadIdx.x;
  const int wave = tid >> 6, lane = tid & 63;
  __shared__ float s_part[2][16];
  __shared__ float s_log[16][OO];

  float mp = V_REST, th = THRESH0, prev = 0.0f, cnt = 0.0f;
  float S = 0.0f;
  const size_t base = (size_t)b * NN + tid;
  const size_t STEP = (size_t)BB * NN;

  // depth-2 prefetch pipeline for net
  float netc = hid[base];                 // t = 0
  float netn = hid[STEP + base];          // t = 1

  for (int t = 0; t < TT; ++t) {
    float rec = -0.5f * (S - prev);       // exact closed-form prev@W_rec
    float nv = netc + rec;                // matches np elementwise add
    float m = mp + (V_REST - mp) / TAU_M; // true division, as reference
    m = m + nv * DT;
    bool spk = (m >= th);
    float s = spk ? 1.0f : 0.0f;
    th = (th + BETA * s) - ((th - THRESH0) / TAU_TH) * DT; // old th both terms
    mp = spk ? V_REST : m;
    cnt += s;
    prev = s;
    hid[(size_t)t * STEP + base] = s;

    // rotate prefetch: issue t+2 now (independent of this step's results)
    float netf = 0.0f;
    if (t + 2 < TT) netf = hid[(size_t)(t + 2) * STEP + base];
    netc = netn;
    netn = netf;

    // row spike count: ballot+popcount per wave, one barrier, parity buffers
    unsigned long long bal = __ballot(spk);
    if (lane == 0) s_part[t & 1][wave] = (float)__popcll(bal);
    __syncthreads();
    const float* sp = s_part[t & 1];
    float4 p0 = *(const float4*)(sp + 0);
    float4 p1 = *(const float4*)(sp + 4);
    float4 p2 = *(const float4*)(sp + 8);
    float4 p3 = *(const float4*)(sp + 12);
    S = ((p0.x + p0.y) + (p0.z + p0.w)) + ((p1.x + p1.y) + (p1.z + p1.w)) +
        ((p2.x + p2.y) + (p2.z + p2.w)) + ((p3.x + p3.y) + (p3.z + p3.w));
  }

  // logits[b,o] = sum_j cnt[b,j] * Wout[j,o]
  float lg[OO];
#pragma unroll
  for (int o = 0; o < OO; ++o) lg[o] = cnt * Wout[(size_t)tid * OO + o];
#pragma unroll
  for (int o = 0; o < OO; ++o) {
    float v = lg[o];
#pragma unroll
    for (int d = 32; d > 0; d >>= 1) v += __shfl_down(v, d, 64);
    if (lane == 0) s_log[wave][o] = v;
  }
  __syncthreads();
  if (tid < OO) {
    float v = 0.0f;
#pragma unroll
    for (int w = 0; w < 16; ++w) v += s_log[w][tid];
    logits[(size_t)b * OO + tid] = v;
  }
}

extern "C" void kernel_launch(void* const* d_in, const int* in_sizes, int n_in,
                              void* d_out, int out_size, void* d_ws,
                              size_t ws_size, hipStream_t stream) {
  const float* X    = (const float*)d_in[0];  // input_spikes [200][256][784]
  const float* Win  = (const float*)d_in[1];  // [784][1024]
  // d_in[2] = W_rec — unused (exact closed form)
  const float* Wout = (const float*)d_in[3];  // [1024][10]

  float* logits = (float*)d_out;              // [256][10]
  float* hid    = (float*)d_out + BB * OO;    // [200][256][1024]

  dim3 g1(NN / 128, TT * BB / 128);           // 8 x 400 blocks
  gemm_net<<<g1, 256, 0, stream>>>(X, Win, hid);
  snn_scan<<<BB, 1024, 0, stream>>>(hid, Wout, logits);
}

// Round 3
// 1238.961 us; speedup vs baseline: 1.1823x; 1.0044x over previous
//
#include <hip/hip_runtime.h>

// SNN: T=200, B=256, IN=784, N=1024, OUT=10
// W_rec = -0.5*(ones - I) => prev@W_rec = -0.5*(S_b - prev[b,j])  (exact in
// fp32: all partial sums are multiples of 0.5 with |.| <= 512).
// net_in[t] = x_t @ W_in is time-independent => one big fp32 GEMM up front
// into d_out's hidden_spikes region, then an in-place spike scan.
//
// NUMERICS CONTRACT: dynamics are knife-edge (absmax 512 of 611 = one
// marginal spike-step flip vs BLAS summation order). The GEMM keeps a single
// ascending-k fmaf chain per output element — bit-identical across rounds.
// No MFMA/bf16, no split-K, no reassociation, true division in the scan.

#define TT 200
#define BB 256
#define KK 784
#define NN 1024
#define OO 10

// ---------------- Phase 1: net = X(51200x784) @ W(784x1024), fp32 ----------
// 128x128 tile, BK=16, 256 threads, 8x8 micro-tile (2x2 quadrants of 4x4).
// Register-prefetch pipeline: tile k+1 is loaded into registers before the
// compute of tile k, so global latency overlaps 1024 FMAs instead of being
// exposed at the barrier's implicit vmcnt(0) drain.
__global__ __launch_bounds__(256)
void gemm_net(const float* __restrict__ X, const float* __restrict__ W,
              float* __restrict__ C) {
  __shared__ float As[16][128];   // [k][m] (A staged transposed)
  __shared__ float Bs[16][128];   // [k][n]
  float4 (*As4)[32] = (float4(*)[32])As;
  float4 (*Bs4)[32] = (float4(*)[32])Bs;

  const int tid = threadIdx.x;
  const int n0 = blockIdx.x * 128;
  const int m0 = blockIdx.y * 128;
  const int tx = tid & 15;             // cols tx*4, 64+tx*4
  const int ty = tid >> 4;             // rows ty*4, 64+ty*4
  const int arow = tid >> 1;           // 0..127
  const int ak   = (tid & 1) * 8;      // 0 or 8
  const int brow = tid >> 5;           // 0..7 (and +8)
  const int bc   = (tid & 31) * 4;     // 0..124

  const float* ap = X + (size_t)(m0 + arow) * KK + ak;
  const float* bp = W + (size_t)brow * NN + n0 + bc;

  // preload tile 0 into registers
  float4 a0 = *(const float4*)(ap);
  float4 a1 = *(const float4*)(ap + 4);
  float4 b0 = *(const float4*)(bp);
  float4 b1 = *(const float4*)(bp + 8 * NN);

  float acc[2][2][4][4] = {};

  for (int k0 = 0; k0 < KK; k0 += 16) {
    __syncthreads();                   // previous tile's LDS reads done
    As[ak + 0][arow] = a0.x;           // bank=arow%32, 2-way (free)
    As[ak + 1][arow] = a0.y;
    As[ak + 2][arow] = a0.z;
    As[ak + 3][arow] = a0.w;
    As[ak + 4][arow] = a1.x;
    As[ak + 5][arow] = a1.y;
    As[ak + 6][arow] = a1.z;
    As[ak + 7][arow] = a1.w;
    *(float4*)&Bs[brow][bc] = b0;      // lane-consecutive: conflict-free
    *(float4*)&Bs[brow + 8][bc] = b1;
    __syncthreads();

    // prefetch next tile (latency overlapped by the 1024 FMAs below)
    if (k0 + 16 < KK) {
      ap += 16;
      bp += 16 * NN;
      a0 = *(const float4*)(ap);
      a1 = *(const float4*)(ap + 4);
      b0 = *(const float4*)(bp);
      b1 = *(const float4*)(bp + 8 * NN);
    }

#pragma unroll
    for (int k = 0; k < 16; ++k) {
      float4 A0 = As4[k][ty];          // broadcast (free)
      float4 A1 = As4[k][16 + ty];
      float4 B0 = Bs4[k][tx];          // 2-way (free)
      float4 B1 = Bs4[k][16 + tx];
      float av[2][4] = {{A0.x, A0.y, A0.z, A0.w}, {A1.x, A1.y, A1.z, A1.w}};
      float bv[2][4] = {{B0.x, B0.y, B0.z, B0.w}, {B1.x, B1.y, B1.z, B1.w}};
#pragma unroll
      for (int qi = 0; qi < 2; ++qi)
#pragma unroll
        for (int qj = 0; qj < 2; ++qj)
#pragma unroll
          for (int i = 0; i < 4; ++i)
#pragma unroll
            for (int j = 0; j < 4; ++j)
              acc[qi][qj][i][j] =
                  fmaf(av[qi][i], bv[qj][j], acc[qi][qj][i][j]);
    }
  }
#pragma unroll
  for (int qi = 0; qi < 2; ++qi)
#pragma unroll
    for (int i = 0; i < 4; ++i) {
      const int r = m0 + qi * 64 + ty * 4 + i;
#pragma unroll
      for (int qj = 0; qj < 2; ++qj) {
        float4 v = {acc[qi][qj][i][0], acc[qi][qj][i][1],
                    acc[qi][qj][i][2], acc[qi][qj][i][3]};
        *(float4*)(C + (size_t)r * NN + n0 + qj * 64 + tx * 4) = v;
      }
    }
}

// ---------------- Phase 2: sequential scan, one block per batch row --------
// 1024 threads (1 neuron each, 16 waves). hid holds net on entry; overwritten
// in place with spikes. One lgkm-only barrier per step (inline asm) so the
// spike stores and depth-2 net prefetch stay in flight across the barrier —
// __syncthreads' implicit vmcnt(0) drain would serialize a global-latency
// round trip into every step.
__global__ __launch_bounds__(1024)
void snn_scan(float* __restrict__ hid, const float* __restrict__ Wout,
              float* __restrict__ logits) {
  constexpr float V_REST = -65.0f, THRESH0 = -50.0f, TAU_M = 20.0f,
                  TAU_TH = 100.0f, BETA = 5.0f, DT = 1.0f;
  const int b = blockIdx.x;
  const int tid = threadIdx.x;
  const int wave = tid >> 6, lane = tid & 63;
  __shared__ float s_part[2][16];
  __shared__ float s_log[16][OO];

  float mp = V_REST, th = THRESH0, prev = 0.0f, cnt = 0.0f;
  float S = 0.0f;
  const size_t base = (size_t)b * NN + tid;
  const size_t STEP = (size_t)BB * NN;

  // depth-2 prefetch pipeline for net
  float netc = hid[base];                 // t = 0
  float netn = hid[STEP + base];          // t = 1

  for (int t = 0; t < TT; ++t) {
    float rec = -0.5f * (S - prev);       // exact closed-form prev@W_rec
    float nv = netc + rec;                // matches np elementwise add order
    float m = mp + (V_REST - mp) / TAU_M; // true division, as reference
    m = m + nv * DT;
    bool spk = (m >= th);
    float s = spk ? 1.0f : 0.0f;
    th = (th + BETA * s) - ((th - THRESH0) / TAU_TH) * DT; // old th both terms
    mp = spk ? V_REST : m;
    cnt += s;
    prev = s;
    hid[(size_t)t * STEP + base] = s;

    // rotate prefetch: issue t+2 now (independent of this step's results)
    float netf = 0.0f;
    if (t + 2 < TT) netf = hid[(size_t)(t + 2) * STEP + base];
    netc = netn;
    netn = netf;

    // row spike count: ballot+popcount per wave; parity-buffered partials;
    // lgkm-only barrier (global loads/stores NOT drained).
    unsigned long long bal = __ballot(spk);
    if (lane == 0) s_part[t & 1][wave] = (float)__popcll(bal);
    __asm__ volatile("s_waitcnt lgkmcnt(0)\n\ts_barrier" ::: "memory");
    const float* sp = s_part[t & 1];
    float4 p0 = *(const float4*)(sp + 0);
    float4 p1 = *(const float4*)(sp + 4);
    float4 p2 = *(const float4*)(sp + 8);
    float4 p3 = *(const float4*)(sp + 12);
    S = ((p0.x + p0.y) + (p0.z + p0.w)) + ((p1.x + p1.y) + (p1.z + p1.w)) +
        ((p2.x + p2.y) + (p2.z + p2.w)) + ((p3.x + p3.y) + (p3.z + p3.w));
  }

  // logits[b,o] = sum_j cnt[b,j] * Wout[j,o]
  float lg[OO];
#pragma unroll
  for (int o = 0; o < OO; ++o) lg[o] = cnt * Wout[(size_t)tid * OO + o];
#pragma unroll
  for (int o = 0; o < OO; ++o) {
    float v = lg[o];
#pragma unroll
    for (int d = 32; d > 0; d >>= 1) v += __shfl_down(v, d, 64);
    if (lane == 0) s_log[wave][o] = v;
  }
  __syncthreads();
  if (tid < OO) {
    float v = 0.0f;
#pragma unroll
    for (int w = 0; w < 16; ++w) v += s_log[w][tid];
    logits[(size_t)b * OO + tid] = v;
  }
}

extern "C" void kernel_launch(void* const* d_in, const int* in_sizes, int n_in,
                              void* d_out, int out_size, void* d_ws,
                              size_t ws_size, hipStream_t stream) {
  const float* X    = (const float*)d_in[0];  // input_spikes [200][256][784]
  const float* Win  = (const float*)d_in[1];  // [784][1024]
  // d_in[2] = W_rec — unused (exact closed form)
  const float* Wout = (const float*)d_in[3];  // [1024][10]

  float* logits = (float*)d_out;              // [256][10]
  float* hid    = (float*)d_out + BB * OO;    // [200][256][1024]

  dim3 g1(NN / 128, TT * BB / 128);           // 8 x 400 blocks
  gemm_net<<<g1, 256, 0, stream>>>(X, Win, hid);
  snn_scan<<<BB, 1024, 0, stream>>>(hid, Wout, logits);
}